// Round 4
// baseline (384.891 us; speedup 1.0000x reference)
//
#include <hip/hip_runtime.h>
#include <hip/hip_bf16.h>

#define HW_   (512 * 512)
#define B_    4
#define D_    64
#define NPIX  (B_ * HW_)          // 1048576
#define NW    19                  // within channels used (20 - 1)
#define NC    26                  // cross channels used  (27 - 1)
#define NSEG  20                  // centroid segments
#define THREADS 256
#define TILE  THREADS             // 1 pixel per thread

// 16 chunks of 4 features; k = partial-dot accumulator index (c & 3)
#define FOREACH_CHUNK(X) \
  X(0,0,f0,f1,f2,f3)      X(1,1,f4,f5,f6,f7)      X(2,2,f8,f9,f10,f11)     X(3,3,f12,f13,f14,f15) \
  X(4,0,f16,f17,f18,f19)  X(5,1,f20,f21,f22,f23)  X(6,2,f24,f25,f26,f27)   X(7,3,f28,f29,f30,f31) \
  X(8,0,f32,f33,f34,f35)  X(9,1,f36,f37,f38,f39)  X(10,2,f40,f41,f42,f43)  X(11,3,f44,f45,f46,f47) \
  X(12,0,f48,f49,f50,f51) X(13,1,f52,f53,f54,f55) X(14,2,f56,f57,f58,f59)  X(15,3,f60,f61,f62,f63)

// online softmax-entropy state update (branchless; init m=-1e30f, S=W=0)
#define ONLINE(m, S, W, a) { \
    float mN = fmaxf(m, a); \
    float c0 = __expf(m - mN); \
    float s0 = (a) - mN; \
    float e0 = __expf(s0); \
    W = fmaf(m - mN, S, W) * c0 + s0 * e0; \
    S = fmaf(S, c0, e0); \
    m = mN; }

__global__ __launch_bounds__(THREADS, 4)
void fused_embed(const float* __restrict__ enc, const float* __restrict__ wW,
                 const float* __restrict__ wC, const int* __restrict__ targ,
                 float* __restrict__ out)
{
    __shared__ float sCent[NSEG][D_ + 1]; // +1 pad: bank = lab*65+c ≡ lab+c (mod 32)
    __shared__ int   sCount[NSEG];
    __shared__ float sRed[THREADS / 64];

    const int tid = threadIdx.x;

    for (int i = tid; i < NSEG * (D_ + 1); i += THREADS) (&sCent[0][0])[i] = 0.f;
    if (tid < NSEG) sCount[tid] = 0;
    __syncthreads();

    const int p   = blockIdx.x * TILE + tid;       // this thread's pixel
    const int b   = (blockIdx.x * TILE) / HW_;     // block never straddles images
    const int hw0 = p - b * HW_;
    const float* fp = enc + (size_t)b * (D_ * HW_) + hw0;
    const int lab = targ[p];

    // ---- load the full 64-dim feature vector into named VGPRs (read-once) ----
#define LOADC(c, k, fa, fb, fc2, fd) \
    float fa = fp[(4*(c)+0) * HW_]; \
    float fb = fp[(4*(c)+1) * HW_]; \
    float fc2 = fp[(4*(c)+2) * HW_]; \
    float fd = fp[(4*(c)+3) * HW_];
    FOREACH_CHUNK(LOADC)
#undef LOADC

    // ---- centroid accumulation (ds_add_f32, no return) ----
#define ATOMC(c, k, fa, fb, fc2, fd) \
    atomicAdd(&sCent[lab][4*(c)+0], fa); \
    atomicAdd(&sCent[lab][4*(c)+1], fb); \
    atomicAdd(&sCent[lab][4*(c)+2], fc2); \
    atomicAdd(&sCent[lab][4*(c)+3], fd);
    FOREACH_CHUNK(ATOMC)
#undef ATOMC
    atomicAdd(&sCount[lab], 1);

    // dot of weight row `wr` (uniform address -> scalar loads) with features
#define DOTC(c, k, fa, fb, fc2, fd) { \
    const float4 w = *(const float4*)(wr + 4*(c)); \
    d##k = fmaf(w.x, fa, d##k); d##k = fmaf(w.y, fb, d##k); \
    d##k = fmaf(w.z, fc2, d##k); d##k = fmaf(w.w, fd, d##k); }

    // ---- within group: stream 19 rows, online entropy ----
    float mW = -1e30f, SW = 0.f, WWt = 0.f;
#pragma unroll 1
    for (int n = 0; n < NW; ++n) {
        const float* wr = wW + n * D_;
        float d0 = 0.f, d1 = 0.f, d2 = 0.f, d3 = 0.f;
        FOREACH_CHUNK(DOTC)
        float a = (d0 + d1) + (d2 + d3);
        ONLINE(mW, SW, WWt, a)
    }

    // ---- cross group: stream 26 rows ----
    float mC = -1e30f, SC = 0.f, WCt = 0.f;
#pragma unroll 1
    for (int n = 0; n < NC; ++n) {
        const float* wr = wC + n * D_;
        float d0 = 0.f, d1 = 0.f, d2 = 0.f, d3 = 0.f;
        FOREACH_CHUNK(DOTC)
        float a = (d0 + d1) + (d2 + d3);
        ONLINE(mC, SC, WCt, a)
    }
#undef DOTC

    float lossAcc = (__logf(SW) - WWt / SW) + (__logf(SC) - WCt / SC);

    // wave reduce (64 lanes)
#pragma unroll
    for (int off = 32; off; off >>= 1) lossAcc += __shfl_down(lossAcc, off);
    if ((tid & 63) == 0) sRed[tid >> 6] = lossAcc;
    __syncthreads();
    if (tid == 0) {
        float s = 0.f;
#pragma unroll
        for (int w = 0; w < THREADS / 64; ++w) s += sRed[w];
        atomicAdd(out, s * (0.5f / (float)NPIX));
    }

    // flush centroids + counts (counts written as float: harness reads f32)
    for (int i = tid; i < NSEG * D_; i += THREADS) {
        int n = i >> 6, d = i & 63;
        atomicAdd(&out[1 + i], sCent[n][d]);
    }
    if (tid < NSEG) atomicAdd(&out[1 + NSEG * D_ + tid], (float)sCount[tid]);
}

extern "C" void kernel_launch(void* const* d_in, const int* in_sizes, int n_in,
                              void* d_out, int out_size, void* d_ws, size_t ws_size,
                              hipStream_t stream) {
    const float* enc = (const float*)d_in[0];
    const float* wW  = (const float*)d_in[1];
    const float* wC  = (const float*)d_in[2];
    const int*   targ = (const int*)d_in[3];
    float* out = (float*)d_out;

    // d_out is poisoned 0xAA once and never re-poisoned; we accumulate with
    // atomics, so zero it every call (memset node is graph-capturable).
    hipMemsetAsync(d_out, 0, (size_t)out_size * sizeof(float), stream);

    fused_embed<<<dim3(NPIX / TILE), dim3(THREADS), 0, stream>>>(enc, wW, wC, targ, out);
}